// Round 1
// baseline (45.773 us; speedup 1.0000x reference)
//
#include <hip/hip_runtime.h>

// Problem constants (from reference setup_inputs)
#define NUM_VARS  256
#define NUM_NODES 65536
#define NUM_CATS  256
#define BATCH     512

// out[node*BATCH + b] = log(params[s_pids[node] + data[vids[node]*BATCH + b]])
__global__ __launch_bounds__(256) void input_layer_kernel(
    const int*   __restrict__ data,    // [NUM_VARS * BATCH] int32
    const float* __restrict__ params,  // [NUM_NODES * NUM_CATS]
    const int*   __restrict__ vids,    // [NUM_NODES]
    const int*   __restrict__ s_pids,  // [NUM_NODES]
    float*       __restrict__ out)     // [NUM_NODES * BATCH] fp32
{
    const int total4 = (NUM_NODES * BATCH) / 4;   // 8,388,608 float4 groups
    const int stride = gridDim.x * blockDim.x;
    for (int i4 = blockIdx.x * blockDim.x + threadIdx.x; i4 < total4; i4 += stride) {
        const int base = i4 << 2;                 // element index, multiple of 4
        const int node = base >> 9;               // BATCH == 512
        const int b    = base & (BATCH - 1);

        const int vid  = vids[node];              // wave-mostly-uniform -> L1 broadcast
        const int spid = s_pids[node];

        // coalesced 16B load of 4 consecutive batch observations
        const int4 dv = *reinterpret_cast<const int4*>(&data[vid * BATCH + b]);

        // 4 gathers within this node's 1KiB param row (L1-resident)
        float4 r;
        r.x = __logf(params[spid + dv.x]);
        r.y = __logf(params[spid + dv.y]);
        r.z = __logf(params[spid + dv.z]);
        r.w = __logf(params[spid + dv.w]);

        // coalesced 16B store
        *reinterpret_cast<float4*>(&out[base]) = r;
    }
}

extern "C" void kernel_launch(void* const* d_in, const int* in_sizes, int n_in,
                              void* d_out, int out_size, void* d_ws, size_t ws_size,
                              hipStream_t stream) {
    const int*   data   = (const int*)d_in[0];
    const float* params = (const float*)d_in[1];
    const int*   vids   = (const int*)d_in[2];
    const int*   s_pids = (const int*)d_in[3];
    float*       out    = (float*)d_out;

    const int block = 256;
    const int total4 = (NUM_NODES * BATCH) / 4;
    int grid = (total4 + block - 1) / block;      // 32768
    if (grid > 2048) grid = 2048;                 // grid-stride cap (256 CU x 8 blocks)

    input_layer_kernel<<<grid, block, 0, stream>>>(data, params, vids, s_pids, out);
}

// Round 3
// 39.229 us; speedup vs baseline: 1.1668x; 1.1668x over previous
//
#include <hip/hip_runtime.h>

// Problem constants (from reference setup_inputs)
#define NUM_VARS  256
#define NUM_NODES 65536
#define NUM_CATS  256
#define BATCH     512
#define NODES_PER_BLOCK 8

typedef __attribute__((ext_vector_type(4))) float f32x4;
typedef __attribute__((ext_vector_type(4))) int   i32x4;

// out[node*BATCH + b] = log(params[s_pids[node] + data[vids[node]*BATCH + b]])
//
// Strategy: per block, stage log(params_row) for 8 nodes in LDS (8 KiB).
//  - Row load: wave w loads row w as ONE coalesced 1KiB float4 wave-instr.
//  - log applied to the 256-entry row (not the 512 gathered values): halves logs.
//  - Gather phase reads data as int4 (coalesced), gathers from LDS (random cats
//    over 32 banks ~2-way, near-free), streams float4 out (nontemporal).
__global__ __launch_bounds__(256) void input_layer_kernel(
    const int*   __restrict__ data,    // [NUM_VARS * BATCH] int32
    const float* __restrict__ params,  // [NUM_NODES * NUM_CATS]
    const int*   __restrict__ vids,    // [NUM_NODES]
    const int*   __restrict__ s_pids,  // [NUM_NODES]
    float*       __restrict__ out)     // [NUM_NODES * BATCH] fp32
{
    __shared__ float logp[NODES_PER_BLOCK * NUM_CATS];   // 8 KiB
    const int t  = threadIdx.x;
    const int gb = blockIdx.x * NODES_PER_BLOCK;         // first node of this block

    // ---- Phase 1: params rows -> log -> LDS ----
    // h=0: rows 0..3 (wave w -> row w), h=1: rows 4..7
#pragma unroll
    for (int h = 0; h < 2; ++h) {
        const int r = (t >> 6) + h * 4;                  // node-local row 0..7
        const int c = (t & 63) * 4;                      // col, step 4
        const int spid = s_pids[gb + r];                 // wave-uniform broadcast
        const f32x4 p = __builtin_nontemporal_load(
            reinterpret_cast<const f32x4*>(&params[spid + c]));
        f32x4 lp;
        lp.x = __logf(p.x); lp.y = __logf(p.y);
        lp.z = __logf(p.z); lp.w = __logf(p.w);
        *reinterpret_cast<f32x4*>(&logp[r * NUM_CATS + c]) = lp;   // stride-16B, conflict-free
    }
    __syncthreads();

    // ---- Phase 2: gather + stream out ----
    // 8 nodes x 512 batch = 4096 outputs; 4 chunks of 1024 (4/thread each)
#pragma unroll
    for (int ch = 0; ch < 4; ++ch) {
        const int e = ch * 1024 + t * 4;                 // element within group
        const int k = e >> 9;                            // node-local 0..7 (wave-uniform)
        const int b = e & (BATCH - 1);
        const int vid = vids[gb + k];                    // wave-uniform broadcast
        const i32x4 dv = *reinterpret_cast<const i32x4*>(&data[vid * BATCH + b]); // coalesced
        f32x4 r;
        r.x = logp[k * NUM_CATS + dv.x];
        r.y = logp[k * NUM_CATS + dv.y];
        r.z = logp[k * NUM_CATS + dv.z];
        r.w = logp[k * NUM_CATS + dv.w];
        __builtin_nontemporal_store(r,
            reinterpret_cast<f32x4*>(&out[(gb + k) * BATCH + b]));  // coalesced stream
    }
}

extern "C" void kernel_launch(void* const* d_in, const int* in_sizes, int n_in,
                              void* d_out, int out_size, void* d_ws, size_t ws_size,
                              hipStream_t stream) {
    const int*   data   = (const int*)d_in[0];
    const float* params = (const float*)d_in[1];
    const int*   vids   = (const int*)d_in[2];
    const int*   s_pids = (const int*)d_in[3];
    float*       out    = (float*)d_out;

    const int block = 256;
    const int grid  = NUM_NODES / NODES_PER_BLOCK;       // 8192 blocks, no tail
    input_layer_kernel<<<grid, block, 0, stream>>>(data, params, vids, s_pids, out);
}